// Round 1
// baseline (660.058 us; speedup 1.0000x reference)
//
#include <hip/hip_runtime.h>
#include <math.h>

#define EPSV 1e-8f

// ws layout:
//   [0, N*16)                      : float4 per node {deg, C=sum cos4phi, S=sum sin4phi, z=#zero dirs}
//   [N*16, N*16 + NODE_BLOCKS*16)  : double2 per node-kernel block {pair_loss_sum, n_pairs}
static constexpr int NODE_BLOCKS = 256;
static constexpr int NODE_THREADS = 256;

__global__ __launch_bounds__(256) void edge_kernel(
    const float2* __restrict__ pos,
    const int* __restrict__ ei,     // (2, E) row-major: src row then dst row
    float* __restrict__ acc,        // float4 per node
    int E)
{
    int tid = blockIdx.x * blockDim.x + threadIdx.x;
    int nthreads = gridDim.x * blockDim.x;
    int nvec = E >> 2;  // E divisible by 4
    const int4* src4 = (const int4*)ei;
    const int4* dst4 = (const int4*)(ei + E);
    for (int v = tid; v < nvec; v += nthreads) {
        int4 sv = src4[v];
        int4 tv = dst4[v];
        int ss[4] = {sv.x, sv.y, sv.z, sv.w};
        int tt[4] = {tv.x, tv.y, tv.z, tv.w};
#pragma unroll
        for (int k = 0; k < 4; ++k) {
            int s = ss[k], t = tt[k];
            float2 ps = pos[s];
            float2 pt = pos[t];
            float dx = pt.x - ps.x;
            float dy = pt.y - ps.y;
            float nrm = sqrtf(dx * dx + dy * dy);
            float inv = 1.0f / fmaxf(nrm, EPSV);
            float nx = dx * inv, ny = dy * inv;
            // angle-quadrupling without trig: (nx,ny)=(cos,sin) -> cos4,sin4
            float c2 = nx * nx - ny * ny;
            float s2 = 2.0f * nx * ny;
            float c4 = c2 * c2 - s2 * s2;
            float s4 = 2.0f * c2 * s2;
            atomicAdd(&acc[4 * s + 0], 1.0f);
            atomicAdd(&acc[4 * s + 1], c4);
            atomicAdd(&acc[4 * s + 2], s4);
            atomicAdd(&acc[4 * t + 0], 1.0f);
            atomicAdd(&acc[4 * t + 1], c4);
            atomicAdd(&acc[4 * t + 2], s4);
            if (!(nrm > EPSV)) {  // zero-length direction (self-edge): rare
                atomicAdd(&acc[4 * s + 3], 1.0f);
                atomicAdd(&acc[4 * t + 3], 1.0f);
            }
        }
    }
}

__global__ __launch_bounds__(NODE_THREADS) void node_kernel(
    const float4* __restrict__ acc,
    double* __restrict__ partials,   // 2 doubles per block
    int N)
{
    int tid = blockIdx.x * blockDim.x + threadIdx.x;
    int nthreads = gridDim.x * blockDim.x;
    double pls = 0.0, npr = 0.0;
    for (int n = tid; n < N; n += nthreads) {
        float4 a = acc[n];
        double deg = (double)a.x;
        double C = (double)a.y;
        double S = (double)a.z;
        double u = deg - (double)a.w;  // unit-direction count
        pls += (u * u - C * C - S * S) * 0.0625;  // 0.5 * (S2-S4), S2-S4 = (u^2-C^2-S^2)/8
        npr += 0.5 * deg * (deg - 1.0);
    }
    // block reduction (4 waves of 64)
    __shared__ double sha[4], shb[4];
    for (int off = 32; off > 0; off >>= 1) {
        pls += __shfl_down(pls, off, 64);
        npr += __shfl_down(npr, off, 64);
    }
    int lane = threadIdx.x & 63;
    int wid = threadIdx.x >> 6;
    if (lane == 0) { sha[wid] = pls; shb[wid] = npr; }
    __syncthreads();
    if (threadIdx.x == 0) {
        double a = sha[0] + sha[1] + sha[2] + sha[3];
        double b = shb[0] + shb[1] + shb[2] + shb[3];
        partials[2 * blockIdx.x + 0] = a;
        partials[2 * blockIdx.x + 1] = b;
    }
}

__global__ __launch_bounds__(256) void final_kernel(
    const double* __restrict__ partials,
    float* __restrict__ out,
    int nb)
{
    double pls = 0.0, npr = 0.0;
    for (int i = threadIdx.x; i < nb; i += blockDim.x) {
        pls += partials[2 * i + 0];
        npr += partials[2 * i + 1];
    }
    __shared__ double sha[4], shb[4];
    for (int off = 32; off > 0; off >>= 1) {
        pls += __shfl_down(pls, off, 64);
        npr += __shfl_down(npr, off, 64);
    }
    int lane = threadIdx.x & 63;
    int wid = threadIdx.x >> 6;
    if (lane == 0) { sha[wid] = pls; shb[wid] = npr; }
    __syncthreads();
    if (threadIdx.x == 0) {
        double a = sha[0] + sha[1] + sha[2] + sha[3];
        double b = shb[0] + shb[1] + shb[2] + shb[3];
        out[0] = (float)(a / fmax(b, 1.0));
    }
}

extern "C" void kernel_launch(void* const* d_in, const int* in_sizes, int n_in,
                              void* d_out, int out_size, void* d_ws, size_t ws_size,
                              hipStream_t stream) {
    const float* pos = (const float*)d_in[0];       // (1, N, 2) -> interleaved x,y
    const int* ei = (const int*)d_in[2];            // (2, E)
    int n_pos = in_sizes[0];                        // 2*N
    int N = n_pos / 2;
    int E = in_sizes[2] / 2;
    float* out = (float*)d_out;

    float* acc = (float*)d_ws;                      // N * float4
    double* partials = (double*)((char*)d_ws + (size_t)N * 16);

    size_t zero_bytes = (size_t)N * 16 + (size_t)NODE_BLOCKS * 16;
    hipMemsetAsync(d_ws, 0, zero_bytes, stream);

    int nvec = E >> 2;
    int eb = (nvec + 255) / 256;
    edge_kernel<<<eb, 256, 0, stream>>>((const float2*)pos, ei, acc, E);
    node_kernel<<<NODE_BLOCKS, NODE_THREADS, 0, stream>>>((const float4*)acc, partials, N);
    final_kernel<<<1, 256, 0, stream>>>(partials, out, NODE_BLOCKS);
}

// Round 2
// 250.089 us; speedup vs baseline: 2.6393x; 2.6393x over previous
//
#include <hip/hip_runtime.h>
#include <math.h>

#define EPSV 1e-8f

// ws layout:
//   [0, N*8)                     : u64 per node, packed {z:4 | deg:8 | c4sum:26 | s4sum:26}
//                                  unit dir adds (1<<52) | (round((c4+1)*2^17)<<26) | round((s4+1)*2^17)
//                                  zero dir adds (1<<60) | (1<<52)
//   [N*8, N*8 + NODE_BLOCKS*16)  : double2 per node-kernel block {pair_loss_sum, n_pairs}
static constexpr int NODE_BLOCKS = 256;
static constexpr int NODE_THREADS = 256;
static constexpr float QSCALE = 131072.0f;          // 2^17
static constexpr double QINV = 1.0 / 131072.0;

__global__ __launch_bounds__(256) void edge_kernel(
    const float2* __restrict__ pos,
    const int* __restrict__ ei,     // (2, E) row-major: src row then dst row
    unsigned long long* __restrict__ acc,
    int E)
{
    int tid = blockIdx.x * blockDim.x + threadIdx.x;
    int nthreads = gridDim.x * blockDim.x;
    int nvec = E >> 2;  // E divisible by 4
    const int4* src4 = (const int4*)ei;
    const int4* dst4 = (const int4*)(ei + E);
    for (int v = tid; v < nvec; v += nthreads) {
        int4 sv = src4[v];
        int4 tv = dst4[v];
        int ss[4] = {sv.x, sv.y, sv.z, sv.w};
        int tt[4] = {tv.x, tv.y, tv.z, tv.w};
#pragma unroll
        for (int k = 0; k < 4; ++k) {
            int s = ss[k], t = tt[k];
            float2 ps = pos[s];
            float2 pt = pos[t];
            float dx = pt.x - ps.x;
            float dy = pt.y - ps.y;
            float n2 = dx * dx + dy * dy;
            unsigned long long val;
            if (n2 > EPSV * EPSV) {
                float inv = 1.0f / sqrtf(n2);
                float nx = dx * inv, ny = dy * inv;
                // angle quadrupling: (nx,ny)=(cos,sin) -> cos4, sin4 without trig
                float c2 = nx * nx - ny * ny;
                float s2 = 2.0f * nx * ny;
                float c4 = c2 * c2 - s2 * s2;
                float s4 = 2.0f * c2 * s2;
                c4 = fminf(fmaxf(c4, -1.0f), 1.0f);
                s4 = fminf(fmaxf(s4, -1.0f), 1.0f);
                unsigned int c4f = (unsigned int)__float2int_rn((c4 + 1.0f) * QSCALE);
                unsigned int s4f = (unsigned int)__float2int_rn((s4 + 1.0f) * QSCALE);
                val = (1ull << 52) | ((unsigned long long)c4f << 26) | (unsigned long long)s4f;
            } else {
                // zero-length direction (self-edge): counts toward deg and z only
                val = (1ull << 60) | (1ull << 52);
            }
            atomicAdd(&acc[s], val);
            atomicAdd(&acc[t], val);
        }
    }
}

__global__ __launch_bounds__(NODE_THREADS) void node_kernel(
    const unsigned long long* __restrict__ acc,
    double* __restrict__ partials,   // 2 doubles per block
    int N)
{
    int tid = blockIdx.x * blockDim.x + threadIdx.x;
    int nthreads = gridDim.x * blockDim.x;
    double pls = 0.0, npr = 0.0;
    for (int n = tid; n < N; n += nthreads) {
        unsigned long long a = acc[n];
        double s4sum = (double)(a & 0x3FFFFFFull);
        double c4sum = (double)((a >> 26) & 0x3FFFFFFull);
        double deg = (double)((a >> 52) & 0xFFull);
        double z = (double)(a >> 60);
        double u = deg - z;                  // unit-direction count
        double C = c4sum * QINV - u;         // sum of cos(4*phi)
        double S = s4sum * QINV - u;         // sum of sin(4*phi)
        pls += (u * u - C * C - S * S) * 0.0625;  // 0.5*(S2-S4); S2-S4=(u^2-C^2-S^2)/8
        npr += 0.5 * deg * (deg - 1.0);
    }
    __shared__ double sha[4], shb[4];
    for (int off = 32; off > 0; off >>= 1) {
        pls += __shfl_down(pls, off, 64);
        npr += __shfl_down(npr, off, 64);
    }
    int lane = threadIdx.x & 63;
    int wid = threadIdx.x >> 6;
    if (lane == 0) { sha[wid] = pls; shb[wid] = npr; }
    __syncthreads();
    if (threadIdx.x == 0) {
        partials[2 * blockIdx.x + 0] = sha[0] + sha[1] + sha[2] + sha[3];
        partials[2 * blockIdx.x + 1] = shb[0] + shb[1] + shb[2] + shb[3];
    }
}

__global__ __launch_bounds__(256) void final_kernel(
    const double* __restrict__ partials,
    float* __restrict__ out,
    int nb)
{
    double pls = 0.0, npr = 0.0;
    for (int i = threadIdx.x; i < nb; i += blockDim.x) {
        pls += partials[2 * i + 0];
        npr += partials[2 * i + 1];
    }
    __shared__ double sha[4], shb[4];
    for (int off = 32; off > 0; off >>= 1) {
        pls += __shfl_down(pls, off, 64);
        npr += __shfl_down(npr, off, 64);
    }
    int lane = threadIdx.x & 63;
    int wid = threadIdx.x >> 6;
    if (lane == 0) { sha[wid] = pls; shb[wid] = npr; }
    __syncthreads();
    if (threadIdx.x == 0) {
        double a = sha[0] + sha[1] + sha[2] + sha[3];
        double b = shb[0] + shb[1] + shb[2] + shb[3];
        out[0] = (float)(a / fmax(b, 1.0));
    }
}

extern "C" void kernel_launch(void* const* d_in, const int* in_sizes, int n_in,
                              void* d_out, int out_size, void* d_ws, size_t ws_size,
                              hipStream_t stream) {
    const float* pos = (const float*)d_in[0];       // (1, N, 2) -> interleaved x,y
    const int* ei = (const int*)d_in[2];            // (2, E)
    int N = in_sizes[0] / 2;
    int E = in_sizes[2] / 2;
    float* out = (float*)d_out;

    unsigned long long* acc = (unsigned long long*)d_ws;           // N u64
    double* partials = (double*)((char*)d_ws + (size_t)N * 8);

    size_t zero_bytes = (size_t)N * 8 + (size_t)NODE_BLOCKS * 16;
    hipMemsetAsync(d_ws, 0, zero_bytes, stream);

    int nvec = E >> 2;
    int eb = (nvec + 255) / 256;
    edge_kernel<<<eb, 256, 0, stream>>>((const float2*)pos, ei, acc, E);
    node_kernel<<<NODE_BLOCKS, NODE_THREADS, 0, stream>>>(acc, partials, N);
    final_kernel<<<1, 256, 0, stream>>>(partials, out, NODE_BLOCKS);
}